// Round 19
// baseline (56.842 us; speedup 1.0000x reference)
//
#include <hip/hip_runtime.h>
#include <cstddef>
#include <cstdint>

#define NROWS  200000
#define CIN    32
#define COUT   64
#define KV     27
#define NWAVES (NROWS / 64)   // 3125

typedef __attribute__((ext_vector_type(8))) short  short8;
typedef __attribute__((ext_vector_type(4))) float  f32x4;

// RNE float -> bf16 (inputs finite)
__device__ __forceinline__ unsigned short f2bf(float x) {
  unsigned u = __builtin_bit_cast(unsigned, x);
  u += 0x7FFFu + ((u >> 16) & 1u);
  return (unsigned short)(u >> 16);
}

// Fused prep: blocks [0,27) pack weight -> bf16 B-fragments in ws;
// blocks [27, 27+3126) convert feats f32 -> bf16 (pad row N = zeros).
__global__ void prep_fused_kernel(const float* __restrict__ w,
                                  const float* __restrict__ feats,
                                  short8* __restrict__ wsB,
                                  short8* __restrict__ fb) {
  const int bid = blockIdx.x;
  const int tid = threadIdx.x;
  if (bid < 27) {
    // weight pack: wsB[(k*4+t)*64+lane][f] = W[k][(lane>>4)*8+f][t*16+(lane&15)]
    int gid = bid * 256 + tid;                       // 6912 total
    int lane = gid & 63;
    int t    = (gid >> 6) & 3;
    int k    = gid >> 8;
    int col  = t * 16 + (lane & 15);
    int kin0 = (lane >> 4) * 8;
    short8 v;
#pragma unroll
    for (int f = 0; f < 8; ++f)
      v[f] = (short)f2bf(w[((size_t)k * CIN + kin0 + f) * COUT + col]);
    wsB[gid] = v;
  } else {
    int i = (bid - 27) * 256 + tid;                  // short8 units
    const int total8 = (NROWS + 1) * CIN / 8;        // 800004
    if (i >= total8) return;
    short8 v = {0, 0, 0, 0, 0, 0, 0, 0};
    if (i < NROWS * CIN / 8) {
      const f32x4* p = (const f32x4*)feats + (size_t)i * 2;
      f32x4 a = p[0], b = p[1];
#pragma unroll
      for (int f = 0; f < 4; ++f) {
        v[f]     = (short)f2bf(a[f]);
        v[4 + f] = (short)f2bf(b[f]);
      }
    }
    fb[i] = v;
  }
}

// Main: R18 champion (Mw=4 wave, idx staged via LDS, single-wave 64-thread
// blocks, compiler-scheduled k-loop) + ONE change: the bf16 gather is
// PREDICATED on idx < NROWS. ~77% of in_idx entries are the pad row (19.5%
// grid occupancy); exec-masked lanes issue no address, so if the TA address
// pipe costs ~1 active lane/cy (the theory that fits the measured 342cy/iter
// per-CU service floor), gather cost drops ~4x. Masked lanes keep a zeroed
// fragment (numerically identical to reading the zero pad row). R15's
// predication test was confounded (fp32 2-line rows + in-loop cvt); this is
// the clean cell.
__global__ __launch_bounds__(64, 4)
void spconv_mfma_kernel(const unsigned short* __restrict__ featsbf,
                        const short8* __restrict__ wsB,
                        const float* __restrict__ bias,
                        const int* __restrict__ in_idx,
                        float* __restrict__ out) {
  __shared__ int sIdx[KV][64];                       // 6,912 B

  const int lane = threadIdx.x & 63;
  const int wid  = (int)blockIdx.x;
  if (wid >= NWAVES) return;
  const int row0 = wid << 6;

  // ---- stage this wave's idx block into LDS ----
  {
    int tmp[KV];
#pragma unroll
    for (int k = 0; k < KV; ++k)
      tmp[k] = in_idx[(size_t)k * NROWS + row0 + lane];
#pragma unroll
    for (int k = 0; k < KV; ++k)
      sIdx[k][lane] = tmp[k];
  }

  const int c16  = lane & 15;
  const int kg   = lane >> 4;
  const int koff = kg * 8;

  f32x4 acc[4][4];                                   // [m][t]
#pragma unroll
  for (int t = 0; t < 4; ++t) {
    float bv = bias[t * 16 + c16];
    f32x4 bvv = {bv, bv, bv, bv};
#pragma unroll
    for (int m = 0; m < 4; ++m) acc[m][t] = bvv;
  }

  const short8* bp = wsB + lane;

  // idx for k=0 (broadcast ds_read: 4 lanes same address -> free)
  int idxc[4], idxn[4];
#pragma unroll
  for (int m = 0; m < 4; ++m) idxc[m] = sIdx[0][m * 16 + c16];

  for (int k = 0; k < KV; ++k) {
    // prefetch idx(k+1) from LDS (off the global-latency path entirely)
    const int kn = (k + 1 < KV) ? k + 1 : KV - 1;
#pragma unroll
    for (int m = 0; m < 4; ++m) idxn[m] = sIdx[kn][m * 16 + c16];

    short8 bfr[4];
#pragma unroll
    for (int t = 0; t < 4; ++t) bfr[t] = bp[(k * 4 + t) * 64];

    short8 afr[4];
#pragma unroll
    for (int m = 0; m < 4; ++m) {
      short8 a = {0, 0, 0, 0, 0, 0, 0, 0};
      if (idxc[m] < NROWS)                           // pad lanes: no request
        a = *(const short8*)(featsbf + (size_t)idxc[m] * CIN + koff);
      afr[m] = a;
    }

#pragma unroll
    for (int m = 0; m < 4; ++m) {
      acc[m][0] = __builtin_amdgcn_mfma_f32_16x16x32_bf16(afr[m], bfr[0], acc[m][0], 0, 0, 0);
      acc[m][1] = __builtin_amdgcn_mfma_f32_16x16x32_bf16(afr[m], bfr[1], acc[m][1], 0, 0, 0);
      acc[m][2] = __builtin_amdgcn_mfma_f32_16x16x32_bf16(afr[m], bfr[2], acc[m][2], 0, 0, 0);
      acc[m][3] = __builtin_amdgcn_mfma_f32_16x16x32_bf16(afr[m], bfr[3], acc[m][3], 0, 0, 0);
    }

#pragma unroll
    for (int m = 0; m < 4; ++m) idxc[m] = idxn[m];
  }

  // D layout: col = t*16 + (lane&15), row = (lane>>4)*4 + r
#pragma unroll
  for (int m = 0; m < 4; ++m)
#pragma unroll
    for (int t = 0; t < 4; ++t)
#pragma unroll
      for (int r = 0; r < 4; ++r)
        out[(size_t)(row0 + m * 16 + kg * 4 + r) * COUT + t * 16 + c16] = acc[m][t][r];
}

// Correct-but-slow fallback if ws is tiny (shouldn't happen).
__global__ void spconv_naive_kernel(const float* __restrict__ feats,
                                    const float* __restrict__ w,
                                    const float* __restrict__ bias,
                                    const int* __restrict__ in_idx,
                                    float* __restrict__ out) {
  int gid = blockIdx.x * blockDim.x + threadIdx.x;
  if (gid >= NROWS * COUT) return;
  int row = gid / COUT, co = gid % COUT;
  float acc = bias[co];
  for (int k = 0; k < KV; ++k) {
    int idx = in_idx[(size_t)k * NROWS + row];
    if (idx < NROWS) {
      const float* fr = feats + (size_t)idx * CIN;
      const float* wk = w + (size_t)k * CIN * COUT + co;
#pragma unroll
      for (int c = 0; c < CIN; ++c) acc += fr[c] * wk[(size_t)c * COUT];
    }
  }
  out[gid] = acc;
}

extern "C" void kernel_launch(void* const* d_in, const int* in_sizes, int n_in,
                              void* d_out, int out_size, void* d_ws, size_t ws_size,
                              hipStream_t stream) {
  const float* feats  = (const float*)d_in[0];
  const float* weight = (const float*)d_in[1];
  const float* bias   = (const float*)d_in[2];
  const int*   in_idx = (const int*)d_in[3];
  float*       out    = (float*)d_out;

  const size_t wsB_bytes = (size_t)KV * 4 * 64 * 16;        // 110592
  const size_t fb_bytes  = (size_t)(NROWS + 1) * CIN * 2;   // 12800064
  short8*         wsB     = (short8*)d_ws;
  unsigned short* featsbf = (unsigned short*)((char*)d_ws + wsB_bytes);

  if (ws_size >= wsB_bytes + fb_bytes) {
    const int prepBlocks = 27 + ((NROWS + 1) * CIN / 8 + 255) / 256;  // 3153
    prep_fused_kernel<<<prepBlocks, 256, 0, stream>>>(
        weight, feats, wsB, (short8*)featsbf);
    spconv_mfma_kernel<<<NWAVES, 64, 0, stream>>>(
        featsbf, wsB, bias, in_idx, out);
  } else {
    spconv_naive_kernel<<<(NROWS * COUT + 255) / 256, 256, 0, stream>>>(
        feats, weight, bias, in_idx, out);
  }
}

// Round 20
// 49.370 us; speedup vs baseline: 1.1513x; 1.1513x over previous
//
#include <hip/hip_runtime.h>
#include <cstddef>
#include <cstdint>

#define NROWS  200000
#define CIN    32
#define COUT   64
#define KV     27
#define NWAVES (NROWS / 64)   // 3125

typedef __attribute__((ext_vector_type(8))) short  short8;
typedef __attribute__((ext_vector_type(4))) float  f32x4;

// RNE float -> bf16 (inputs finite)
__device__ __forceinline__ unsigned short f2bf(float x) {
  unsigned u = __builtin_bit_cast(unsigned, x);
  u += 0x7FFFu + ((u >> 16) & 1u);
  return (unsigned short)(u >> 16);
}

// Fused prep: blocks [0,27) pack weight -> bf16 B-fragments in ws;
// blocks [27, 27+3126) convert feats f32 -> bf16 (pad row N = zeros).
__global__ void prep_fused_kernel(const float* __restrict__ w,
                                  const float* __restrict__ feats,
                                  short8* __restrict__ wsB,
                                  short8* __restrict__ fb) {
  const int bid = blockIdx.x;
  const int tid = threadIdx.x;
  if (bid < 27) {
    // weight pack: wsB[(k*4+t)*64+lane][f] = W[k][(lane>>4)*8+f][t*16+(lane&15)]
    int gid = bid * 256 + tid;                       // 6912 total
    int lane = gid & 63;
    int t    = (gid >> 6) & 3;
    int k    = gid >> 8;
    int col  = t * 16 + (lane & 15);
    int kin0 = (lane >> 4) * 8;
    short8 v;
#pragma unroll
    for (int f = 0; f < 8; ++f)
      v[f] = (short)f2bf(w[((size_t)k * CIN + kin0 + f) * COUT + col]);
    wsB[gid] = v;
  } else {
    int i = (bid - 27) * 256 + tid;                  // short8 units
    const int total8 = (NROWS + 1) * CIN / 8;        // 800004
    if (i >= total8) return;
    short8 v = {0, 0, 0, 0, 0, 0, 0, 0};
    if (i < NROWS * CIN / 8) {
      const f32x4* p = (const f32x4*)feats + (size_t)i * 2;
      f32x4 a = p[0], b = p[1];
#pragma unroll
      for (int f = 0; f < 4; ++f) {
        v[f]     = (short)f2bf(a[f]);
        v[4 + f] = (short)f2bf(b[f]);
      }
    }
    fb[i] = v;
  }
}

// Main: R18 champion VERBATIM — Mw=4 wave, idx staged via LDS, single-wave
// 64-thread blocks, compiler-scheduled k-loop, UNPREDICATED bf16 gathers
// (R19 proved per-lane masking regresses: divergent exec-mask flow breaks
// the gather clusters; the pad-row read is L1-broadcast and nearly free).
__global__ __launch_bounds__(64, 4)
void spconv_mfma_kernel(const unsigned short* __restrict__ featsbf,
                        const short8* __restrict__ wsB,
                        const float* __restrict__ bias,
                        const int* __restrict__ in_idx,
                        float* __restrict__ out) {
  __shared__ int sIdx[KV][64];                       // 6,912 B

  const int lane = threadIdx.x & 63;
  const int wid  = (int)blockIdx.x;
  if (wid >= NWAVES) return;
  const int row0 = wid << 6;

  // ---- stage this wave's idx block into LDS ----
  {
    int tmp[KV];
#pragma unroll
    for (int k = 0; k < KV; ++k)
      tmp[k] = in_idx[(size_t)k * NROWS + row0 + lane];
#pragma unroll
    for (int k = 0; k < KV; ++k)
      sIdx[k][lane] = tmp[k];
  }

  const int c16  = lane & 15;
  const int kg   = lane >> 4;
  const int koff = kg * 8;

  f32x4 acc[4][4];                                   // [m][t]
#pragma unroll
  for (int t = 0; t < 4; ++t) {
    float bv = bias[t * 16 + c16];
    f32x4 bvv = {bv, bv, bv, bv};
#pragma unroll
    for (int m = 0; m < 4; ++m) acc[m][t] = bvv;
  }

  const short8* bp = wsB + lane;

  // idx for k=0 (broadcast ds_read: 4 lanes same address -> free)
  int idxc[4], idxn[4];
#pragma unroll
  for (int m = 0; m < 4; ++m) idxc[m] = sIdx[0][m * 16 + c16];

  for (int k = 0; k < KV; ++k) {
    // prefetch idx(k+1) from LDS (off the global-latency path entirely)
    const int kn = (k + 1 < KV) ? k + 1 : KV - 1;
#pragma unroll
    for (int m = 0; m < 4; ++m) idxn[m] = sIdx[kn][m * 16 + c16];

    short8 bfr[4];
#pragma unroll
    for (int t = 0; t < 4; ++t) bfr[t] = bp[(k * 4 + t) * 64];

    short8 afr[4];
#pragma unroll
    for (int m = 0; m < 4; ++m)
      afr[m] = *(const short8*)(featsbf + (size_t)idxc[m] * CIN + koff);

#pragma unroll
    for (int m = 0; m < 4; ++m) {
      acc[m][0] = __builtin_amdgcn_mfma_f32_16x16x32_bf16(afr[m], bfr[0], acc[m][0], 0, 0, 0);
      acc[m][1] = __builtin_amdgcn_mfma_f32_16x16x32_bf16(afr[m], bfr[1], acc[m][1], 0, 0, 0);
      acc[m][2] = __builtin_amdgcn_mfma_f32_16x16x32_bf16(afr[m], bfr[2], acc[m][2], 0, 0, 0);
      acc[m][3] = __builtin_amdgcn_mfma_f32_16x16x32_bf16(afr[m], bfr[3], acc[m][3], 0, 0, 0);
    }

#pragma unroll
    for (int m = 0; m < 4; ++m) idxc[m] = idxn[m];
  }

  // D layout: col = t*16 + (lane&15), row = (lane>>4)*4 + r
#pragma unroll
  for (int m = 0; m < 4; ++m)
#pragma unroll
    for (int t = 0; t < 4; ++t)
#pragma unroll
      for (int r = 0; r < 4; ++r)
        out[(size_t)(row0 + m * 16 + kg * 4 + r) * COUT + t * 16 + c16] = acc[m][t][r];
}

// Correct-but-slow fallback if ws is tiny (shouldn't happen).
__global__ void spconv_naive_kernel(const float* __restrict__ feats,
                                    const float* __restrict__ w,
                                    const float* __restrict__ bias,
                                    const int* __restrict__ in_idx,
                                    float* __restrict__ out) {
  int gid = blockIdx.x * blockDim.x + threadIdx.x;
  if (gid >= NROWS * COUT) return;
  int row = gid / COUT, co = gid % COUT;
  float acc = bias[co];
  for (int k = 0; k < KV; ++k) {
    int idx = in_idx[(size_t)k * NROWS + row];
    if (idx < NROWS) {
      const float* fr = feats + (size_t)idx * CIN;
      const float* wk = w + (size_t)k * CIN * COUT + co;
#pragma unroll
      for (int c = 0; c < CIN; ++c) acc += fr[c] * wk[(size_t)c * COUT];
    }
  }
  out[gid] = acc;
}

extern "C" void kernel_launch(void* const* d_in, const int* in_sizes, int n_in,
                              void* d_out, int out_size, void* d_ws, size_t ws_size,
                              hipStream_t stream) {
  const float* feats  = (const float*)d_in[0];
  const float* weight = (const float*)d_in[1];
  const float* bias   = (const float*)d_in[2];
  const int*   in_idx = (const int*)d_in[3];
  float*       out    = (float*)d_out;

  const size_t wsB_bytes = (size_t)KV * 4 * 64 * 16;        // 110592
  const size_t fb_bytes  = (size_t)(NROWS + 1) * CIN * 2;   // 12800064
  short8*         wsB     = (short8*)d_ws;
  unsigned short* featsbf = (unsigned short*)((char*)d_ws + wsB_bytes);

  if (ws_size >= wsB_bytes + fb_bytes) {
    const int prepBlocks = 27 + ((NROWS + 1) * CIN / 8 + 255) / 256;  // 3153
    prep_fused_kernel<<<prepBlocks, 256, 0, stream>>>(
        weight, feats, wsB, (short8*)featsbf);
    spconv_mfma_kernel<<<NWAVES, 64, 0, stream>>>(
        featsbf, wsB, bias, in_idx, out);
  } else {
    spconv_naive_kernel<<<(NROWS * COUT + 255) / 256, 256, 0, stream>>>(
        feats, weight, bias, in_idx, out);
  }
}